// Round 7
// baseline (570.341 us; speedup 1.0000x reference)
//
#include <hip/hip_runtime.h>

// GraphSAGE 2-layer, N=100000, E=1600000, F=128. Inputs f32; src/dst int32.
//
// Pipeline (CSR path):
//   memset(cnt); count; scan1/2/3 -> row[NN+1]; cursor=row; fill CSR (int2
//   packed edge records: one 8B store/edge — round-6 fill was 2x 4B random
//   stores, 154 MB WRITE_SIZE for a 12.8 MB array);
//   wprep: Wcat bf16; conv: infbf = bf16(in_feat) in H1BF slot
//   gather1: sbf = bf16(mean_w in-nbrs)  (packed uint loads, 8-deep unroll)
//   gemm1:  h1bf = relu(...) MFMA, IN-PLACE over infbf (disjoint row tiles)
//   gather2: sbf from h1bf
//   gemm2:  d_out f32
//
// MFMA 16x16x32_bf16 (m89): A lane l: A[m=l&15][k=(l>>4)*8+j];
// B lane l: B[k=(l>>4)*8+j][n=l&15] == W[n][k] row-major; C/D col=l&15,
// row=(l>>4)*4+r.

#define NN 100000
#define NE 1600000
#define F 128

#define SCAN_BS 1024
#define NBLK ((NN + SCAN_BS - 1) / SCAN_BS)   // 98

// ---- ws layout (bytes) ----
static const size_t CNT_OFF   = 0;          // int[NN] counters -> fill cursor
static const size_t ROW_OFF   = 400000;     // int[NN+1]
static const size_t BSUM_OFF  = 800016;     // int[NBLK]
static const size_t EDGE_OFF  = 804112;     // int2[NE] (src, w bits) 12.8 MB
static const size_t WCAT1_OFF = 13604112;   // bf16[128*256]
static const size_t WCAT2_OFF = 13669648;   // bf16[128*256]
static const size_t SBF_OFF   = 13735184;   // bf16[NN*F]
static const size_t H1BF_OFF  = 39335184;   // bf16[NN*F]  (infbf then h1bf)
static const size_t WS_NEED   = 64935184;

// ---- fallback layout ----
static const size_t FB_S_OFF = 524288;      // deg f32[NN] @0, s f32[NN*F]

typedef __attribute__((ext_vector_type(8))) short short8;
typedef __attribute__((ext_vector_type(4))) float float4v;

__device__ __forceinline__ float bf2f(unsigned int u16) {
    unsigned int x = u16 << 16;
    float f;
    __builtin_memcpy(&f, &x, 4);
    return f;
}
__device__ __forceinline__ unsigned int f2bf(float f) {
    unsigned int x;
    __builtin_memcpy(&x, &f, 4);
    unsigned int r = x + 0x7FFFu + ((x >> 16) & 1u);
    return r >> 16;
}

// ======================= CSR build =======================

__global__ __launch_bounds__(256) void count_kernel(const int* __restrict__ dst,
                                                    int* __restrict__ cnt) {
    int e = blockIdx.x * 256 + threadIdx.x;
    if (e < NE) atomicAdd(&cnt[dst[e]], 1);
}

__global__ __launch_bounds__(256) void scan1_kernel(const int* __restrict__ cnt,
                                                    int* __restrict__ part,
                                                    int* __restrict__ bsum) {
    __shared__ int ts[256];
    int t = threadIdx.x;
    int base = blockIdx.x * SCAN_BS + t * 4;
    int c0 = (base     < NN) ? cnt[base]     : 0;
    int c1 = (base + 1 < NN) ? cnt[base + 1] : 0;
    int c2 = (base + 2 < NN) ? cnt[base + 2] : 0;
    int c3 = (base + 3 < NN) ? cnt[base + 3] : 0;
    int sum = c0 + c1 + c2 + c3;
    ts[t] = sum;
    __syncthreads();
    for (int off = 1; off < 256; off <<= 1) {
        int u = (t >= off) ? ts[t - off] : 0;
        __syncthreads();
        ts[t] += u;
        __syncthreads();
    }
    int excl = ts[t] - sum;
    if (t == 255) bsum[blockIdx.x] = ts[255];
    if (base     < NN) part[base]     = excl;
    if (base + 1 < NN) part[base + 1] = excl + c0;
    if (base + 2 < NN) part[base + 2] = excl + c0 + c1;
    if (base + 3 < NN) part[base + 3] = excl + c0 + c1 + c2;
}

__global__ void scan2_kernel(int* __restrict__ bsum) {
    if (threadIdx.x == 0 && blockIdx.x == 0) {
        int acc = 0;
        for (int i = 0; i < NBLK; i++) { int v = bsum[i]; bsum[i] = acc; acc += v; }
    }
}

__global__ __launch_bounds__(256) void scan3_kernel(int* __restrict__ part,
                                                    const int* __restrict__ bsum) {
    int i = blockIdx.x * 256 + threadIdx.x;
    if (i < NN) part[i] += bsum[i / SCAN_BS];
    if (i == 0) part[NN] = NE;
}

__global__ __launch_bounds__(256) void copy_kernel(const int* __restrict__ row,
                                                   int* __restrict__ cursor) {
    int i = blockIdx.x * 256 + threadIdx.x;
    if (i < NN) cursor[i] = row[i];
}

__global__ __launch_bounds__(256) void fill_kernel(const int* __restrict__ src,
                                                   const int* __restrict__ dst,
                                                   const float* __restrict__ w,
                                                   int* __restrict__ cursor,
                                                   int2* __restrict__ edge) {
    int e = blockIdx.x * 256 + threadIdx.x;
    if (e >= NE) return;
    int d = dst[e];
    int pos = atomicAdd(&cursor[d], 1);
    int2 r;
    r.x = src[e];
    r.y = __float_as_int(w[e]);
    edge[pos] = r;
}

// ======================= weight / input prep =======================

__global__ __launch_bounds__(256) void wprep_kernel(const float* __restrict__ Ws,
                                                    const float* __restrict__ Wn,
                                                    unsigned short* __restrict__ wcat) {
    int idx = blockIdx.x * 256 + threadIdx.x;   // 32768
    if (idx >= 128 * 256) return;
    int n = idx >> 8, k = idx & 255;
    float v = (k < 128) ? Ws[n * 128 + k] : Wn[n * 128 + (k - 128)];
    wcat[idx] = (unsigned short)f2bf(v);
}

// f32 -> bf16, 8 elems/thread (NN*F = 12.8M, divisible by 8*256)
__global__ __launch_bounds__(256) void conv_bf16(const float* __restrict__ in,
                                                 unsigned short* __restrict__ outbf) {
    size_t base = ((size_t)blockIdx.x * 256 + threadIdx.x) * 8;
    float4 a = *(const float4*)(in + base);
    float4 b = *(const float4*)(in + base + 4);
    uint4 p;
    p.x = f2bf(a.x) | (f2bf(a.y) << 16);
    p.y = f2bf(a.z) | (f2bf(a.w) << 16);
    p.z = f2bf(b.x) | (f2bf(b.y) << 16);
    p.w = f2bf(b.z) | (f2bf(b.w) << 16);
    *(uint4*)(outbf + base) = p;
}

// ======================= gather (packed bf16, int2 edges) =======================
// 4 nodes per 256-block; 64 threads/node; thread owns features 2l, 2l+1.
// beg/end are readfirstlane'd -> edge[e] addresses are SGPR-uniform (scalar
// loads); 8 row loads in flight per unrolled iteration.
__global__ __launch_bounds__(256) void gather_packed(const unsigned short* __restrict__ h,
                                                     const int* __restrict__ row,
                                                     const int2* __restrict__ edge,
                                                     unsigned short* __restrict__ sbf) {
    int t = threadIdx.x;
    int lane = t & 63;
    int n = blockIdx.x * 4 + (t >> 6);           // NN divisible by 4
    int beg = __builtin_amdgcn_readfirstlane(row[n]);
    int end = __builtin_amdgcn_readfirstlane(row[n + 1]);
    const unsigned int* hp = (const unsigned int*)h;   // row stride 64 uints

    float ax = 0.0f, ay = 0.0f;
    int e = beg;
    for (; e + 7 < end; e += 8) {
        int2 m[8];
#pragma unroll
        for (int i = 0; i < 8; i++) m[i] = edge[e + i];
        unsigned int p[8];
#pragma unroll
        for (int i = 0; i < 8; i++) p[i] = hp[(size_t)m[i].x * 64 + lane];
#pragma unroll
        for (int i = 0; i < 8; i++) {
            float wf = __int_as_float(m[i].y);
            ax += wf * bf2f(p[i] & 0xFFFFu);
            ay += wf * bf2f(p[i] >> 16);
        }
    }
    for (; e < end; e++) {
        int2 m0 = edge[e];
        unsigned int p0 = hp[(size_t)m0.x * 64 + lane];
        float wf = __int_as_float(m0.y);
        ax += wf * bf2f(p0 & 0xFFFFu);
        ay += wf * bf2f(p0 >> 16);
    }
    float invd = 1.0f / fmaxf((float)(end - beg), 1.0f);
    unsigned int outp = f2bf(ax * invd) | (f2bf(ay * invd) << 16);
    ((unsigned int*)sbf)[(size_t)n * 64 + lane] = outp;
}

// ======================= MFMA GEMM =======================
// 256 threads = 4 waves; 128-row M-tile x 128 cols; wave w: rows [w*32,w*32+32)
// as 2x8 grid of 16x16 tiles. K=256 = self(128) ‖ neigh(128).
// self_bf/out_bf NOT __restrict__ — gemm1 runs in-place (out_bf == self_bf).
#define APAD 40   // LDS row stride in bf16 (32 data + 8 pad)

__global__ __launch_bounds__(256) void mfma_gemm(
    const unsigned short* self_bf,               // bf16 [NN,F]
    const unsigned short* __restrict__ sbf,      // bf16 [NN,F] normalized neigh
    const unsigned short* __restrict__ wcat,     // bf16 [128][256]
    const float* __restrict__ bias,              // f32 [128]
    unsigned short* out_bf,                      // layer1: relu+bf16 (or null)
    float* __restrict__ out_f32)                 // layer2: f32 (or null)
{
    __shared__ unsigned short At[128][APAD];

    int t = threadIdx.x;
    int l = t & 63;
    int w = t >> 6;
    int base = blockIdx.x * 128;
    int lane16 = l & 15;
    int quad = l >> 4;

    float4v acc0[8], acc1[8];
#pragma unroll
    for (int ct = 0; ct < 8; ct++) {
        acc0[ct] = (float4v){0.f, 0.f, 0.f, 0.f};
        acc1[ct] = (float4v){0.f, 0.f, 0.f, 0.f};
    }

    for (int half = 0; half < 2; half++) {
        const unsigned short* srcb = (half == 0) ? self_bf : sbf;
        for (int kk = 0; kk < 4; kk++) {
            int k0 = kk * 32;
            __syncthreads();
            for (int idx = t; idx < 512; idx += 256) {
                int m = idx >> 2, q = idx & 3;
                int row = base + m;
                uint4 v = make_uint4(0u, 0u, 0u, 0u);
                if (row < NN) v = *(const uint4*)(srcb + (size_t)row * F + k0 + q * 8);
                *(uint4*)&At[m][q * 8] = v;
            }
            __syncthreads();

            short8 a0 = *(const short8*)&At[w * 32 + lane16][quad * 8];
            short8 a1 = *(const short8*)&At[w * 32 + 16 + lane16][quad * 8];
#pragma unroll
            for (int ct = 0; ct < 8; ct++) {
                short8 b = *(const short8*)(wcat +
                    (size_t)(ct * 16 + lane16) * 256 + half * 128 + k0 + quad * 8);
                acc0[ct] = __builtin_amdgcn_mfma_f32_16x16x32_bf16(a0, b, acc0[ct], 0, 0, 0);
                acc1[ct] = __builtin_amdgcn_mfma_f32_16x16x32_bf16(a1, b, acc1[ct], 0, 0, 0);
            }
        }
    }

    int rowb0 = base + w * 32 + quad * 4;
    int rowb1 = rowb0 + 16;
#pragma unroll
    for (int ct = 0; ct < 8; ct++) {
        int col = ct * 16 + lane16;
        float bc = bias[col];
#pragma unroll
        for (int r = 0; r < 4; r++) {
            int g0 = rowb0 + r, g1 = rowb1 + r;
            float v0 = acc0[ct][r] + bc;
            float v1 = acc1[ct][r] + bc;
            if (out_bf) {
                v0 = fmaxf(v0, 0.0f);
                v1 = fmaxf(v1, 0.0f);
                if (g0 < NN) out_bf[(size_t)g0 * F + col] = (unsigned short)f2bf(v0);
                if (g1 < NN) out_bf[(size_t)g1 * F + col] = (unsigned short)f2bf(v1);
            } else {
                if (g0 < NN) out_f32[(size_t)g0 * F + col] = v0;
                if (g1 < NN) out_f32[(size_t)g1 * F + col] = v1;
            }
        }
    }
}

// ======================= fallback (f32 atomic path) =======================

__global__ __launch_bounds__(256) void scatter_kernel(const float* __restrict__ h,
                                                      const float* __restrict__ w,
                                                      const int* __restrict__ src,
                                                      const int* __restrict__ dst,
                                                      float* __restrict__ s,
                                                      float* __restrict__ deg,
                                                      int add_deg) {
    int e = blockIdx.x * 4 + (threadIdx.x >> 6);
    int lane = threadIdx.x & 63;
    int sn = src[e];
    int dn = dst[e];
    float wf = w[e];
    float2 p = *(const float2*)(h + (size_t)sn * F + lane * 2);
    float* sp = s + (size_t)dn * F + lane * 2;
    unsafeAtomicAdd(sp,     wf * p.x);
    unsafeAtomicAdd(sp + 1, wf * p.y);
    if (add_deg && lane == 0) unsafeAtomicAdd(&deg[dn], 1.0f);
}

__global__ __launch_bounds__(256) void sage_gemm(const float* h,
                                                 const float* __restrict__ s,
                                                 const float* deg,
                                                 const float* __restrict__ Ws,
                                                 const float* __restrict__ bias,
                                                 const float* __restrict__ Wn,
                                                 float* out,
                                                 int relu) {
    __shared__ float xs[16][F];
    __shared__ float invd[16];
    int t = threadIdx.x;
    int j = t & 127;
    int g = t >> 7;
    int base = blockIdx.x * 16;
    for (int idx = t; idx < 16 * 32; idx += 256) {
        int n = idx >> 5, kq = idx & 31;
        *(float4*)&xs[n][kq * 4] = *(const float4*)(h + (size_t)(base + n) * F + kq * 4);
    }
    if (t < 16) invd[t] = deg ? 1.0f / fmaxf(deg[base + t], 1.0f) : 1.0f;
    __syncthreads();
    float acc[8];
#pragma unroll
    for (int i = 0; i < 8; i++) acc[i] = 0.0f;
    for (int kc = 0; kc < F; kc += 4) {
        float4 wv = *(const float4*)(Ws + j * F + kc);
#pragma unroll
        for (int i = 0; i < 8; i++) {
            const float* xr = &xs[g * 8 + i][kc];
            acc[i] += xr[0] * wv.x + xr[1] * wv.y + xr[2] * wv.z + xr[3] * wv.w;
        }
    }
    __syncthreads();
    for (int idx = t; idx < 16 * 32; idx += 256) {
        int n = idx >> 5, kq = idx & 31;
        float4 sv = *(const float4*)(s + (size_t)(base + n) * F + kq * 4);
        float iv = invd[n];
        xs[n][kq * 4]     = sv.x * iv;
        xs[n][kq * 4 + 1] = sv.y * iv;
        xs[n][kq * 4 + 2] = sv.z * iv;
        xs[n][kq * 4 + 3] = sv.w * iv;
    }
    __syncthreads();
    for (int kc = 0; kc < F; kc += 4) {
        float4 wv = *(const float4*)(Wn + j * F + kc);
#pragma unroll
        for (int i = 0; i < 8; i++) {
            const float* xr = &xs[g * 8 + i][kc];
            acc[i] += xr[0] * wv.x + xr[1] * wv.y + xr[2] * wv.z + xr[3] * wv.w;
        }
    }
    float bj = bias[j];
#pragma unroll
    for (int i = 0; i < 8; i++) {
        int n = base + g * 8 + i;
        float v = acc[i] + bj;
        if (relu) v = fmaxf(v, 0.0f);
        out[(size_t)n * F + j] = v;
    }
}

extern "C" void kernel_launch(void* const* d_in, const int* in_sizes, int n_in,
                              void* d_out, int out_size, void* d_ws, size_t ws_size,
                              hipStream_t stream) {
    const float* in_feat = (const float*)d_in[0];
    const float* weights = (const float*)d_in[1];
    const int* src = (const int*)d_in[2];
    const int* dst = (const int*)d_in[3];
    const float* Ws1 = (const float*)d_in[4];
    const float* b1  = (const float*)d_in[5];
    const float* Wn1 = (const float*)d_in[6];
    const float* Ws2 = (const float*)d_in[7];
    const float* b2  = (const float*)d_in[8];
    const float* Wn2 = (const float*)d_in[9];
    float* out = (float*)d_out;

    if (ws_size >= WS_NEED) {
        int* cnt    = (int*)((char*)d_ws + CNT_OFF);
        int* row    = (int*)((char*)d_ws + ROW_OFF);
        int* bsum   = (int*)((char*)d_ws + BSUM_OFF);
        int2* edge  = (int2*)((char*)d_ws + EDGE_OFF);
        unsigned short* wcat1 = (unsigned short*)((char*)d_ws + WCAT1_OFF);
        unsigned short* wcat2 = (unsigned short*)((char*)d_ws + WCAT2_OFF);
        unsigned short* sbf   = (unsigned short*)((char*)d_ws + SBF_OFF);
        unsigned short* hbf   = (unsigned short*)((char*)d_ws + H1BF_OFF); // infbf -> h1bf

        hipMemsetAsync(cnt, 0, 400000, stream);
        count_kernel<<<(NE + 255) / 256, 256, 0, stream>>>(dst, cnt);
        scan1_kernel<<<NBLK, 256, 0, stream>>>(cnt, row, bsum);
        scan2_kernel<<<1, 64, 0, stream>>>(bsum);
        scan3_kernel<<<(NN + 255) / 256, 256, 0, stream>>>(row, bsum);
        copy_kernel<<<(NN + 255) / 256, 256, 0, stream>>>(row, cnt);
        fill_kernel<<<(NE + 255) / 256, 256, 0, stream>>>(src, dst, weights, cnt, edge);
        wprep_kernel<<<128, 256, 0, stream>>>(Ws1, Wn1, wcat1);
        wprep_kernel<<<128, 256, 0, stream>>>(Ws2, Wn2, wcat2);
        conv_bf16<<<6250, 256, 0, stream>>>(in_feat, hbf);

        // layer 1 (gemm1 in-place over hbf: infbf -> h1bf)
        gather_packed<<<NN / 4, 256, 0, stream>>>(hbf, row, edge, sbf);
        mfma_gemm<<<(NN + 127) / 128, 256, 0, stream>>>(hbf, sbf, wcat1, b1, hbf, nullptr);
        // layer 2
        gather_packed<<<NN / 4, 256, 0, stream>>>(hbf, row, edge, sbf);
        mfma_gemm<<<(NN + 127) / 128, 256, 0, stream>>>(hbf, sbf, wcat2, b2, nullptr, out);
    } else {
        float* deg = (float*)d_ws;
        float* s   = (float*)((char*)d_ws + FB_S_OFF);
        hipMemsetAsync(d_ws, 0, FB_S_OFF + (size_t)NN * F * 4, stream);
        scatter_kernel<<<NE / 4, 256, 0, stream>>>(in_feat, weights, src, dst, s, deg, 1);
        sage_gemm<<<NN / 16, 256, 0, stream>>>(in_feat, s, deg, Ws1, b1, Wn1, out, 1);
        hipMemsetAsync(s, 0, (size_t)NN * F * 4, stream);
        scatter_kernel<<<NE / 4, 256, 0, stream>>>(out, weights, src, dst, s, deg, 0);
        sage_gemm<<<NN / 16, 256, 0, stream>>>(out, s, deg, Ws2, b2, Wn2, out, 0);
    }
}

// Round 8
// 508.995 us; speedup vs baseline: 1.1205x; 1.1205x over previous
//
#include <hip/hip_runtime.h>

// GraphSAGE 2-layer, N=100000, E=1600000, F=128. Inputs f32; src/dst int32.
//
// CSR build is a two-level counting sort (round-7 single-pass fill was
// line-thrash bound: 1.6M random 8B stores -> 100 MB of unmerged 64B
// writebacks = 107 µs at scattered-write BW):
//   count + scan -> row[NN+1]
//   bcur_init: bucket cursor[b] = row[b*512]        (bucket = 512-node range)
//   bscatter:  per-block LDS histogram -> one global reservation per bucket
//              -> edges stored in per-block contiguous runs (L2-merged)
//   fine_fill: one block per bucket; LDS per-node cursors; random writes
//              confined to the bucket's ~65 KB L2-resident window
// Then: wprep (bf16 Wself‖Wneigh), conv (in_feat->bf16),
//   gather1 -> sbf; MFMA gemm1 (in-place infbf->h1bf); gather2; gemm2 -> f32.
//
// MFMA 16x16x32_bf16 (m89): A lane l: A[m=l&15][k=(l>>4)*8+j];
// B lane l: B[k=(l>>4)*8+j][n=l&15] == W[n][k] row-major; C/D col=l&15,
// row=(l>>4)*4+r.

#define NN 100000
#define NE 1600000
#define F 128

#define SCAN_BS 1024
#define NBLK ((NN + SCAN_BS - 1) / SCAN_BS)   // 98

#define NPB 512                                // nodes per bucket (pow2)
#define NBUK ((NN + NPB - 1) / NPB)            // 196 buckets
#define EPB 4096                               // edges per bscatter block
#define NBLK3 ((NE + EPB - 1) / EPB)           // 391

// ---- ws layout (bytes) ----
static const size_t CNT_OFF   = 0;          // int[NN]: counts, later bucket cursors
static const size_t ROW_OFF   = 400000;     // int[NN+1]
static const size_t BSUM_OFF  = 800016;     // int[NBLK]
static const size_t EDGE_OFF  = 804112;     // int2[NE] final CSR records, 12.8 MB
static const size_t WCAT1_OFF = 13604112;   // bf16[128*256]
static const size_t WCAT2_OFF = 13669648;   // bf16[128*256]
static const size_t SBF_OFF   = 13735184;   // bf16[NN*F]; ALSO ebuf int2[NE] early
static const size_t H1BF_OFF  = 39335184;   // bf16[NN*F]  (infbf then h1bf)
static const size_t WS_NEED   = 64935184;

// ---- fallback layout ----
static const size_t FB_S_OFF = 524288;      // deg f32[NN] @0, s f32[NN*F]

typedef __attribute__((ext_vector_type(8))) short short8;
typedef __attribute__((ext_vector_type(4))) float float4v;

__device__ __forceinline__ float bf2f(unsigned int u16) {
    unsigned int x = u16 << 16;
    float f;
    __builtin_memcpy(&f, &x, 4);
    return f;
}
__device__ __forceinline__ unsigned int f2bf(float f) {
    unsigned int x;
    __builtin_memcpy(&x, &f, 4);
    unsigned int r = x + 0x7FFFu + ((x >> 16) & 1u);
    return r >> 16;
}

// ======================= degree count + scan =======================

__global__ __launch_bounds__(256) void count_kernel(const int* __restrict__ dst,
                                                    int* __restrict__ cnt) {
    int e = blockIdx.x * 256 + threadIdx.x;
    if (e < NE) atomicAdd(&cnt[dst[e]], 1);
}

__global__ __launch_bounds__(256) void scan1_kernel(const int* __restrict__ cnt,
                                                    int* __restrict__ part,
                                                    int* __restrict__ bsum) {
    __shared__ int ts[256];
    int t = threadIdx.x;
    int base = blockIdx.x * SCAN_BS + t * 4;
    int c0 = (base     < NN) ? cnt[base]     : 0;
    int c1 = (base + 1 < NN) ? cnt[base + 1] : 0;
    int c2 = (base + 2 < NN) ? cnt[base + 2] : 0;
    int c3 = (base + 3 < NN) ? cnt[base + 3] : 0;
    int sum = c0 + c1 + c2 + c3;
    ts[t] = sum;
    __syncthreads();
    for (int off = 1; off < 256; off <<= 1) {
        int u = (t >= off) ? ts[t - off] : 0;
        __syncthreads();
        ts[t] += u;
        __syncthreads();
    }
    int excl = ts[t] - sum;
    if (t == 255) bsum[blockIdx.x] = ts[255];
    if (base     < NN) part[base]     = excl;
    if (base + 1 < NN) part[base + 1] = excl + c0;
    if (base + 2 < NN) part[base + 2] = excl + c0 + c1;
    if (base + 3 < NN) part[base + 3] = excl + c0 + c1 + c2;
}

__global__ void scan2_kernel(int* __restrict__ bsum) {
    if (threadIdx.x == 0 && blockIdx.x == 0) {
        int acc = 0;
        for (int i = 0; i < NBLK; i++) { int v = bsum[i]; bsum[i] = acc; acc += v; }
    }
}

__global__ __launch_bounds__(256) void scan3_kernel(int* __restrict__ part,
                                                    const int* __restrict__ bsum) {
    int i = blockIdx.x * 256 + threadIdx.x;
    if (i < NN) part[i] += bsum[i / SCAN_BS];
    if (i == 0) part[NN] = NE;
}

// ======================= two-level CSR fill =======================

// bucket cursors (reuse cnt region; counts are dead after scan1)
__global__ void bcur_init(const int* __restrict__ row, int* __restrict__ bcur) {
    int b = threadIdx.x;
    if (b < NBUK) bcur[b] = row[b * NPB];
}

// Level 1: block-local multisplit into 196 dst-buckets.
// rec.x = src(17b) | dst_local(9b)<<17 ; rec.y = w bits.
__global__ __launch_bounds__(256) void bscatter(const int* __restrict__ src,
                                                const int* __restrict__ dst,
                                                const float* __restrict__ w,
                                                int* __restrict__ bcur,
                                                int2* __restrict__ ebuf) {
    __shared__ int2 rec[EPB];
    __shared__ unsigned char bid[EPB];
    __shared__ int hist[NBUK];
    __shared__ int gbase[NBUK];
    __shared__ int cur[NBUK];

    int t = threadIdx.x;
    for (int i = t; i < NBUK; i += 256) { hist[i] = 0; cur[i] = 0; }
    __syncthreads();

    int base_e = blockIdx.x * EPB;
#pragma unroll
    for (int i = 0; i < 16; i++) {
        int idx = i * 256 + t;
        int e = base_e + idx;
        if (e < NE) {
            int d = dst[e];
            int b = d >> 9;                 // NPB = 512
            int2 r;
            r.x = src[e] | ((d & 511) << 17);
            r.y = __float_as_int(w[e]);
            rec[idx] = r;
            bid[idx] = (unsigned char)b;
            atomicAdd(&hist[b], 1);
        } else {
            bid[idx] = 255;
        }
    }
    __syncthreads();

    for (int i = t; i < NBUK; i += 256)
        if (hist[i] > 0) gbase[i] = atomicAdd(&bcur[i], hist[i]);
    __syncthreads();

#pragma unroll
    for (int i = 0; i < 16; i++) {
        int idx = i * 256 + t;
        int b = bid[idx];
        if (b != 255) {
            int r = atomicAdd(&cur[b], 1);
            ebuf[gbase[b] + r] = rec[idx];
        }
    }
}

// Level 2: one block per bucket; per-node LDS cursors; writes stay inside
// the bucket's contiguous CSR window (L2-resident -> merged writebacks).
__global__ __launch_bounds__(256) void fine_fill(const int* __restrict__ row,
                                                 const int2* __restrict__ ebuf,
                                                 int2* __restrict__ edge) {
    __shared__ int lcur[NPB];
    int b = blockIdx.x;
    int t = threadIdx.x;
    int n0 = b * NPB;
    int n1 = min(n0 + NPB, NN);
    for (int i = t; i < n1 - n0; i += 256) lcur[i] = row[n0 + i];
    __syncthreads();
    int beg = row[n0], end = row[n1];
    for (int e = beg + t; e < end; e += 256) {
        int2 r = ebuf[e];
        int dl = (r.x >> 17) & 511;
        int pos = atomicAdd(&lcur[dl], 1);
        int2 o;
        o.x = r.x & 0x1FFFF;
        o.y = r.y;
        edge[pos] = o;
    }
}

// ======================= weight / input prep =======================

__global__ __launch_bounds__(256) void wprep_kernel(const float* __restrict__ Ws,
                                                    const float* __restrict__ Wn,
                                                    unsigned short* __restrict__ wcat) {
    int idx = blockIdx.x * 256 + threadIdx.x;   // 32768
    if (idx >= 128 * 256) return;
    int n = idx >> 8, k = idx & 255;
    float v = (k < 128) ? Ws[n * 128 + k] : Wn[n * 128 + (k - 128)];
    wcat[idx] = (unsigned short)f2bf(v);
}

__global__ __launch_bounds__(256) void conv_bf16(const float* __restrict__ in,
                                                 unsigned short* __restrict__ outbf) {
    size_t base = ((size_t)blockIdx.x * 256 + threadIdx.x) * 8;
    float4 a = *(const float4*)(in + base);
    float4 b = *(const float4*)(in + base + 4);
    uint4 p;
    p.x = f2bf(a.x) | (f2bf(a.y) << 16);
    p.y = f2bf(a.z) | (f2bf(a.w) << 16);
    p.z = f2bf(b.x) | (f2bf(b.y) << 16);
    p.w = f2bf(b.z) | (f2bf(b.w) << 16);
    *(uint4*)(outbf + base) = p;
}

// ======================= gather (packed bf16, int2 edges) =======================
__global__ __launch_bounds__(256) void gather_packed(const unsigned short* __restrict__ h,
                                                     const int* __restrict__ row,
                                                     const int2* __restrict__ edge,
                                                     unsigned short* __restrict__ sbf) {
    int t = threadIdx.x;
    int lane = t & 63;
    int n = blockIdx.x * 4 + (t >> 6);           // NN divisible by 4
    int beg = __builtin_amdgcn_readfirstlane(row[n]);
    int end = __builtin_amdgcn_readfirstlane(row[n + 1]);
    const unsigned int* hp = (const unsigned int*)h;   // row stride 64 uints

    float ax = 0.0f, ay = 0.0f;
    int e = beg;
    for (; e + 7 < end; e += 8) {
        int2 m[8];
#pragma unroll
        for (int i = 0; i < 8; i++) m[i] = edge[e + i];
        unsigned int p[8];
#pragma unroll
        for (int i = 0; i < 8; i++) p[i] = hp[(size_t)m[i].x * 64 + lane];
#pragma unroll
        for (int i = 0; i < 8; i++) {
            float wf = __int_as_float(m[i].y);
            ax += wf * bf2f(p[i] & 0xFFFFu);
            ay += wf * bf2f(p[i] >> 16);
        }
    }
    for (; e < end; e++) {
        int2 m0 = edge[e];
        unsigned int p0 = hp[(size_t)m0.x * 64 + lane];
        float wf = __int_as_float(m0.y);
        ax += wf * bf2f(p0 & 0xFFFFu);
        ay += wf * bf2f(p0 >> 16);
    }
    float invd = 1.0f / fmaxf((float)(end - beg), 1.0f);
    unsigned int outp = f2bf(ax * invd) | (f2bf(ay * invd) << 16);
    ((unsigned int*)sbf)[(size_t)n * 64 + lane] = outp;
}

// ======================= MFMA GEMM =======================
#define APAD 40   // LDS row stride in bf16 (32 data + 8 pad)

__global__ __launch_bounds__(256) void mfma_gemm(
    const unsigned short* self_bf,               // bf16 [NN,F] (may alias out_bf)
    const unsigned short* __restrict__ sbf,      // bf16 [NN,F] normalized neigh
    const unsigned short* __restrict__ wcat,     // bf16 [128][256]
    const float* __restrict__ bias,              // f32 [128]
    unsigned short* out_bf,                      // layer1: relu+bf16 (or null)
    float* __restrict__ out_f32)                 // layer2: f32 (or null)
{
    __shared__ unsigned short At[128][APAD];

    int t = threadIdx.x;
    int l = t & 63;
    int w = t >> 6;
    int base = blockIdx.x * 128;
    int lane16 = l & 15;
    int quad = l >> 4;

    float4v acc0[8], acc1[8];
#pragma unroll
    for (int ct = 0; ct < 8; ct++) {
        acc0[ct] = (float4v){0.f, 0.f, 0.f, 0.f};
        acc1[ct] = (float4v){0.f, 0.f, 0.f, 0.f};
    }

    for (int half = 0; half < 2; half++) {
        const unsigned short* srcb = (half == 0) ? self_bf : sbf;
        for (int kk = 0; kk < 4; kk++) {
            int k0 = kk * 32;
            __syncthreads();
            for (int idx = t; idx < 512; idx += 256) {
                int m = idx >> 2, q = idx & 3;
                int row = base + m;
                uint4 v = make_uint4(0u, 0u, 0u, 0u);
                if (row < NN) v = *(const uint4*)(srcb + (size_t)row * F + k0 + q * 8);
                *(uint4*)&At[m][q * 8] = v;
            }
            __syncthreads();

            short8 a0 = *(const short8*)&At[w * 32 + lane16][quad * 8];
            short8 a1 = *(const short8*)&At[w * 32 + 16 + lane16][quad * 8];
#pragma unroll
            for (int ct = 0; ct < 8; ct++) {
                short8 b = *(const short8*)(wcat +
                    (size_t)(ct * 16 + lane16) * 256 + half * 128 + k0 + quad * 8);
                acc0[ct] = __builtin_amdgcn_mfma_f32_16x16x32_bf16(a0, b, acc0[ct], 0, 0, 0);
                acc1[ct] = __builtin_amdgcn_mfma_f32_16x16x32_bf16(a1, b, acc1[ct], 0, 0, 0);
            }
        }
    }

    int rowb0 = base + w * 32 + quad * 4;
    int rowb1 = rowb0 + 16;
#pragma unroll
    for (int ct = 0; ct < 8; ct++) {
        int col = ct * 16 + lane16;
        float bc = bias[col];
#pragma unroll
        for (int r = 0; r < 4; r++) {
            int g0 = rowb0 + r, g1 = rowb1 + r;
            float v0 = acc0[ct][r] + bc;
            float v1 = acc1[ct][r] + bc;
            if (out_bf) {
                v0 = fmaxf(v0, 0.0f);
                v1 = fmaxf(v1, 0.0f);
                if (g0 < NN) out_bf[(size_t)g0 * F + col] = (unsigned short)f2bf(v0);
                if (g1 < NN) out_bf[(size_t)g1 * F + col] = (unsigned short)f2bf(v1);
            } else {
                if (g0 < NN) out_f32[(size_t)g0 * F + col] = v0;
                if (g1 < NN) out_f32[(size_t)g1 * F + col] = v1;
            }
        }
    }
}

// ======================= fallback (f32 atomic path) =======================

__global__ __launch_bounds__(256) void scatter_kernel(const float* __restrict__ h,
                                                      const float* __restrict__ w,
                                                      const int* __restrict__ src,
                                                      const int* __restrict__ dst,
                                                      float* __restrict__ s,
                                                      float* __restrict__ deg,
                                                      int add_deg) {
    int e = blockIdx.x * 4 + (threadIdx.x >> 6);
    int lane = threadIdx.x & 63;
    int sn = src[e];
    int dn = dst[e];
    float wf = w[e];
    float2 p = *(const float2*)(h + (size_t)sn * F + lane * 2);
    float* sp = s + (size_t)dn * F + lane * 2;
    unsafeAtomicAdd(sp,     wf * p.x);
    unsafeAtomicAdd(sp + 1, wf * p.y);
    if (add_deg && lane == 0) unsafeAtomicAdd(&deg[dn], 1.0f);
}

__global__ __launch_bounds__(256) void sage_gemm(const float* h,
                                                 const float* __restrict__ s,
                                                 const float* deg,
                                                 const float* __restrict__ Ws,
                                                 const float* __restrict__ bias,
                                                 const float* __restrict__ Wn,
                                                 float* out,
                                                 int relu) {
    __shared__ float xs[16][F];
    __shared__ float invd[16];
    int t = threadIdx.x;
    int j = t & 127;
    int g = t >> 7;
    int base = blockIdx.x * 16;
    for (int idx = t; idx < 16 * 32; idx += 256) {
        int n = idx >> 5, kq = idx & 31;
        *(float4*)&xs[n][kq * 4] = *(const float4*)(h + (size_t)(base + n) * F + kq * 4);
    }
    if (t < 16) invd[t] = deg ? 1.0f / fmaxf(deg[base + t], 1.0f) : 1.0f;
    __syncthreads();
    float acc[8];
#pragma unroll
    for (int i = 0; i < 8; i++) acc[i] = 0.0f;
    for (int kc = 0; kc < F; kc += 4) {
        float4 wv = *(const float4*)(Ws + j * F + kc);
#pragma unroll
        for (int i = 0; i < 8; i++) {
            const float* xr = &xs[g * 8 + i][kc];
            acc[i] += xr[0] * wv.x + xr[1] * wv.y + xr[2] * wv.z + xr[3] * wv.w;
        }
    }
    __syncthreads();
    for (int idx = t; idx < 16 * 32; idx += 256) {
        int n = idx >> 5, kq = idx & 31;
        float4 sv = *(const float4*)(s + (size_t)(base + n) * F + kq * 4);
        float iv = invd[n];
        xs[n][kq * 4]     = sv.x * iv;
        xs[n][kq * 4 + 1] = sv.y * iv;
        xs[n][kq * 4 + 2] = sv.z * iv;
        xs[n][kq * 4 + 3] = sv.w * iv;
    }
    __syncthreads();
    for (int kc = 0; kc < F; kc += 4) {
        float4 wv = *(const float4*)(Wn + j * F + kc);
#pragma unroll
        for (int i = 0; i < 8; i++) {
            const float* xr = &xs[g * 8 + i][kc];
            acc[i] += xr[0] * wv.x + xr[1] * wv.y + xr[2] * wv.z + xr[3] * wv.w;
        }
    }
    float bj = bias[j];
#pragma unroll
    for (int i = 0; i < 8; i++) {
        int n = base + g * 8 + i;
        float v = acc[i] + bj;
        if (relu) v = fmaxf(v, 0.0f);
        out[(size_t)n * F + j] = v;
    }
}

extern "C" void kernel_launch(void* const* d_in, const int* in_sizes, int n_in,
                              void* d_out, int out_size, void* d_ws, size_t ws_size,
                              hipStream_t stream) {
    const float* in_feat = (const float*)d_in[0];
    const float* weights = (const float*)d_in[1];
    const int* src = (const int*)d_in[2];
    const int* dst = (const int*)d_in[3];
    const float* Ws1 = (const float*)d_in[4];
    const float* b1  = (const float*)d_in[5];
    const float* Wn1 = (const float*)d_in[6];
    const float* Ws2 = (const float*)d_in[7];
    const float* b2  = (const float*)d_in[8];
    const float* Wn2 = (const float*)d_in[9];
    float* out = (float*)d_out;

    if (ws_size >= WS_NEED) {
        int* cnt    = (int*)((char*)d_ws + CNT_OFF);    // counts, then bucket cursors
        int* row    = (int*)((char*)d_ws + ROW_OFF);
        int* bsum   = (int*)((char*)d_ws + BSUM_OFF);
        int2* edge  = (int2*)((char*)d_ws + EDGE_OFF);
        unsigned short* wcat1 = (unsigned short*)((char*)d_ws + WCAT1_OFF);
        unsigned short* wcat2 = (unsigned short*)((char*)d_ws + WCAT2_OFF);
        unsigned short* sbf   = (unsigned short*)((char*)d_ws + SBF_OFF);
        int2* ebuf  = (int2*)((char*)d_ws + SBF_OFF);   // aliases sbf (dead until gather1)
        unsigned short* hbf   = (unsigned short*)((char*)d_ws + H1BF_OFF); // infbf -> h1bf

        hipMemsetAsync(cnt, 0, 400000, stream);
        count_kernel<<<(NE + 255) / 256, 256, 0, stream>>>(dst, cnt);
        scan1_kernel<<<NBLK, 256, 0, stream>>>(cnt, row, bsum);
        scan2_kernel<<<1, 64, 0, stream>>>(bsum);
        scan3_kernel<<<(NN + 255) / 256, 256, 0, stream>>>(row, bsum);
        bcur_init<<<1, 256, 0, stream>>>(row, cnt);     // cnt reused as bucket cursors
        bscatter<<<NBLK3, 256, 0, stream>>>(src, dst, weights, cnt, ebuf);
        fine_fill<<<NBUK, 256, 0, stream>>>(row, ebuf, edge);
        wprep_kernel<<<128, 256, 0, stream>>>(Ws1, Wn1, wcat1);
        wprep_kernel<<<128, 256, 0, stream>>>(Ws2, Wn2, wcat2);
        conv_bf16<<<6250, 256, 0, stream>>>(in_feat, hbf);

        // layer 1 (gemm1 in-place over hbf: infbf -> h1bf)
        gather_packed<<<NN / 4, 256, 0, stream>>>(hbf, row, edge, sbf);
        mfma_gemm<<<(NN + 127) / 128, 256, 0, stream>>>(hbf, sbf, wcat1, b1, hbf, nullptr);
        // layer 2
        gather_packed<<<NN / 4, 256, 0, stream>>>(hbf, row, edge, sbf);
        mfma_gemm<<<(NN + 127) / 128, 256, 0, stream>>>(hbf, sbf, wcat2, b2, nullptr, out);
    } else {
        float* deg = (float*)d_ws;
        float* s   = (float*)((char*)d_ws + FB_S_OFF);
        hipMemsetAsync(d_ws, 0, FB_S_OFF + (size_t)NN * F * 4, stream);
        scatter_kernel<<<NE / 4, 256, 0, stream>>>(in_feat, weights, src, dst, s, deg, 1);
        sage_gemm<<<NN / 16, 256, 0, stream>>>(in_feat, s, deg, Ws1, b1, Wn1, out, 1);
        hipMemsetAsync(s, 0, (size_t)NN * F * 4, stream);
        scatter_kernel<<<NE / 4, 256, 0, stream>>>(out, weights, src, dst, s, deg, 0);
        sage_gemm<<<NN / 16, 256, 0, stream>>>(out, s, deg, Ws2, b2, Wn2, out, 0);
    }
}